// Round 1
// baseline (576.244 us; speedup 1.0000x reference)
//
#include <hip/hip_runtime.h>

// Local2d (unshared conv): B=64, C_IN=64, C_OUT=128, K=3, H=W=32, pad=1, stride=1
// out[b,o,h,w] = sum_{i,ky,kx} weight[o,h,w,i,ky,kx] * xpad[b,i,h+ky-1,w+kx-1] + bias[o,h,w]
//
// Per-location GEMM: M=64 (batch), N=128 (cout), Kdim=576 (i*9+ky*3+kx ==
// weight's contiguous inner layout). One block per location, 4 waves, each
// wave owns 32 couts (2 N-tiles of 16) x all 64 batch (4 M-tiles of 16),
// mfma_f32_16x16x32_bf16, fp32->bf16 on the fly.
//
// A (patches) staged in LDS in fragment order, in 2 K-chunks of 288
// (36,864 B static LDS). B (weights) streamed global->reg->cvt->mfma with
// NO barriers in the K-loop.

typedef __bf16  bf16x8  __attribute__((ext_vector_type(8)));
typedef float   floatx4 __attribute__((ext_vector_type(4)));

static __device__ inline bf16x8 cvt8(floatx4 a, floatx4 b) {
    bf16x8 r;
    r[0] = (__bf16)a[0]; r[1] = (__bf16)a[1]; r[2] = (__bf16)a[2]; r[3] = (__bf16)a[3];
    r[4] = (__bf16)b[0]; r[5] = (__bf16)b[1]; r[6] = (__bf16)b[2]; r[7] = (__bf16)b[3];
    return r;
}

__global__ __launch_bounds__(256, 2) void local2d_kernel(
    const float* __restrict__ x,       // [64,64,32,32]
    const float* __restrict__ weight,  // [128,32,32,64,3,3]
    const float* __restrict__ bias,    // [128,32,32]
    float* __restrict__ out)           // [64,128,32,32]
{
    // A-fragment LDS: [tc(9)][mt(4)][lane(64)][j(8)] bf16 = 36,864 B
    __shared__ __bf16 alds[9 * 4 * 64 * 8];

    const int tid  = threadIdx.x;
    const int lane = tid & 63;
    const int wv   = tid >> 6;          // wave 0..3
    const int ll   = lane & 15;
    const int q    = lane >> 4;         // quad 0..3

    // XCD swizzle: blockIdx%8 = XCD (heuristic); give each XCD 4 contiguous
    // h-rows so out-line writes (contiguous in w) merge in one XCD's L2.
    int bid = blockIdx.x;
    int loc = ((bid & 7) << 7) | (bid >> 3);   // 0..1023
    int h = loc >> 5, w = loc & 31;

    const int o_base = wv * 32;
    // weight rows for this wave's two N-tiles; lane ll picks the o within tile
    const float* wrow0 = weight + ((size_t)(o_base + ll) * 1024 + loc) * 576;
    const float* wrow1 = wrow0 + (size_t)16 * 1024 * 576;
    const int kq = q * 8;               // this lane's k offset within a 32-step

    floatx4 acc[2][4];
    #pragma unroll
    for (int a = 0; a < 2; ++a)
        #pragma unroll
        for (int m = 0; m < 4; ++m)
            acc[a][m] = (floatx4){0.f, 0.f, 0.f, 0.f};

    for (int c = 0; c < 2; ++c) {
        // ---- stage A chunk c: i in [c*32, c*32+32) -> kdim [c*288, c*288+288)
        for (int p = tid; p < 2048; p += 256) {
            int b  = p >> 5;
            int il = p & 31;
            int i  = (c << 5) | il;
            int kbase = il * 9;                        // chunk-local kdim base
            const float* xp = x + ((size_t)b * 64 + i) * 1024;
            int mt      = b >> 4;
            int lane_lo = b & 15;
            #pragma unroll
            for (int ky = 0; ky < 3; ++ky) {
                int y = h + ky - 1;
                bool yok = (unsigned)y < 32u;
                #pragma unroll
                for (int kx = 0; kx < 3; ++kx) {
                    int xc = w + kx - 1;
                    float v = (yok && (unsigned)xc < 32u) ? xp[y * 32 + xc] : 0.0f;
                    int kd = kbase + ky * 3 + kx;      // 0..287
                    int tc = kd >> 5;                  // 0..8
                    int r  = kd & 31;
                    int lw = ((r >> 3) << 4) | lane_lo;
                    int j  = r & 7;
                    alds[((((tc << 2) + mt) << 6) | lw) * 8 + j] = (__bf16)v;
                }
            }
        }
        __syncthreads();

        // ---- K loop over this chunk: 9 steps of K=32, no barriers inside
        const float* wp0 = wrow0 + c * 288 + kq;
        const float* wp1 = wrow1 + c * 288 + kq;
        #pragma unroll 3
        for (int t = 0; t < 9; ++t) {
            floatx4 b0a = *(const floatx4*)(wp0 + t * 32);
            floatx4 b0b = *(const floatx4*)(wp0 + t * 32 + 4);
            floatx4 b1a = *(const floatx4*)(wp1 + t * 32);
            floatx4 b1b = *(const floatx4*)(wp1 + t * 32 + 4);
            bf16x8 bf0 = cvt8(b0a, b0b);
            bf16x8 bf1 = cvt8(b1a, b1b);
            #pragma unroll
            for (int mt = 0; mt < 4; ++mt) {
                bf16x8 af = *(const bf16x8*)&alds[((((t << 2) + mt) << 6) | lane) * 8];
                acc[0][mt] = __builtin_amdgcn_mfma_f32_16x16x32_bf16(af, bf0, acc[0][mt], 0, 0, 0);
                acc[1][mt] = __builtin_amdgcn_mfma_f32_16x16x32_bf16(af, bf1, acc[1][mt], 0, 0, 0);
            }
        }
        __syncthreads();
    }

    // ---- epilogue: bias + scattered stores (C/D: col=lane&15, row=q*4+reg)
    #pragma unroll
    for (int ntl = 0; ntl < 2; ++ntl) {
        int o = o_base + ntl * 16 + ll;
        float bv = bias[(size_t)o * 1024 + loc];
        #pragma unroll
        for (int mt = 0; mt < 4; ++mt) {
            #pragma unroll
            for (int r = 0; r < 4; ++r) {
                int m = (mt << 4) + (q << 2) + r;
                out[((size_t)m * 128 + o) * 1024 + loc] = acc[ntl][mt][r] + bv;
            }
        }
    }
}

extern "C" void kernel_launch(void* const* d_in, const int* in_sizes, int n_in,
                              void* d_out, int out_size, void* d_ws, size_t ws_size,
                              hipStream_t stream) {
    const float* x  = (const float*)d_in[0];
    const float* wt = (const float*)d_in[1];
    const float* bi = (const float*)d_in[2];
    float* out = (float*)d_out;
    local2d_kernel<<<dim3(1024), dim3(256), 0, stream>>>(x, wt, bi, out);
}